// Round 4
// baseline (249.731 us; speedup 1.0000x reference)
//
#include <hip/hip_runtime.h>

// ---------------- problem constants ----------------
#define NFFT    2048
#define HOPSZ   512
#define BATCH   8
#define TFRAMES 2048
#define FBINS   1025
#define OUTLEN  1048064           // HOP*(T-1)
#define TOTALP  1050112           // NFFT + HOP*(T-1)
#define KPAD    2080              // 1056 (even class) + 1024 (odd class)
#define KEVEN   1056              // [Re even 512 | Im even 512 | Re1024 | Im1024 | pad 30]
#define MROWS   16384             // BATCH*TFRAMES
#define KSTEPS  65
#define KS_E    33                // even-class K-steps (33*32 = 1056)
#define NCOLS   1024              // radix-2: compute a in [0,1024) only

typedef float  f32x4  __attribute__((ext_vector_type(4)));
typedef __bf16 bf16x8 __attribute__((ext_vector_type(8)));

typedef __attribute__((address_space(3))) void       lds_void;
typedef const __attribute__((address_space(1))) void gmem_void;

__device__ __forceinline__ unsigned short f2bf(float f) {
    unsigned u = __float_as_uint(f);
    u += 0x7fffu + ((u >> 16) & 1u);       // round-to-nearest-even
    return (unsigned short)(u >> 16);
}

// ---------------- W2[ks][a][32]: packed-K bf16 IDFT weights (NO window) -----
// k' < 1056 (even class): e=k' : e<512 -> Re bin 2e (cos); e<1024 -> Im bin
//   2(e-512) (-sin); e==1024 -> Re bin 1024; e==1025 -> Im bin 1024; else 0.
// k' >= 1056 (odd class): o=k'-1056 : o<512 -> Re bin 2o+1; else Im bin 2(o-512)+1.
__global__ void build_w(unsigned short* __restrict__ W2) {
    int kc = blockIdx.x * 256 + threadIdx.x;     // 8-elem chunk
    if (kc >= KPAD / 8) return;
    int a  = blockIdx.y;                          // [0,1024)
    int k0 = kc * 8;
    unsigned short v[8];
    #pragma unroll
    for (int j = 0; j < 8; ++j) {
        int kp = k0 + j;
        int bin; bool isSin; bool valid = true;
        if (kp < KEVEN) {
            int e = kp;
            if      (e < 512)  { bin = 2 * e;          isSin = false; }
            else if (e < 1024) { bin = 2 * (e - 512);  isSin = true;  }
            else if (e == 1024){ bin = 1024;           isSin = false; }
            else if (e == 1025){ bin = 1024;           isSin = true;  }
            else { valid = false; bin = 0; isSin = false; }
        } else {
            int o = kp - KEVEN;
            if (o < 512) { bin = 2 * o + 1;         isSin = false; }
            else         { bin = 2 * (o - 512) + 1; isSin = true;  }
        }
        float f = 0.0f;
        if (valid) {
            int   m = (bin * a) & 2047;
            float c = (bin == 0 || bin == 1024) ? 1.0f : 2.0f;
            float tr = isSin ? -sinpif((float)m * (1.0f / 1024.0f))
                             :  cospif((float)m * (1.0f / 1024.0f));
            f = c * tr * (1.0f / 2048.0f);
        }
        v[j] = f2bf(f);
    }
    *(uint4*)(W2 + ((size_t)(k0 >> 5) * NCOLS + a) * 32 + (k0 & 31)) = *(const uint4*)v;
}

// ---------------- X2[ks][bt][32]: packed-K bf16 inputs ----------------------
__global__ void conv_x(const float* __restrict__ re, const float* __restrict__ im,
                       unsigned short* __restrict__ X2) {
    const int bt  = blockIdx.x;
    const int tid = threadIdx.x;
    const bool isIm = tid >= 128;
    const int  t8   = tid & 127;                  // bins [8*t8, 8*t8+8)
    const float* src = (isIm ? im : re) + (size_t)bt * FBINS;

    float f[8];
    #pragma unroll
    for (int j = 0; j < 8; ++j) f[j] = src[t8 * 8 + j];

    unsigned short ev[4], od[4];
    #pragma unroll
    for (int i = 0; i < 4; ++i) { ev[i] = f2bf(f[2 * i]); od[i] = f2bf(f[2 * i + 1]); }

    const int e0 = (isIm ? 512 : 0) + t8 * 4;            // even-class k' (mult of 4)
    const int o0 = KEVEN + (isIm ? 512 : 0) + t8 * 4;    // odd-class  k' (mult of 4)
    *(uint2*)(X2 + ((size_t)(e0 >> 5) * MROWS + bt) * 32 + (e0 & 31)) = *(const uint2*)ev;
    *(uint2*)(X2 + ((size_t)(o0 >> 5) * MROWS + bt) * 32 + (o0 & 31)) = *(const uint2*)od;

    // extras: k'=1024 (Re bin 1024), k'=1025 (Im bin 1024), k' 1026..1055 zero
    if (tid < 30)
        X2[((size_t)((1026 + tid) >> 5) * MROWS + bt) * 32 + ((1026 + tid) & 31)] = 0;
    else if (tid == 30)
        X2[((size_t)(1024 >> 5) * MROWS + bt) * 32 + (1024 & 31)] = f2bf(re[(size_t)bt * FBINS + 1024]);
    else if (tid == 31)
        X2[((size_t)(1025 >> 5) * MROWS + bt) * 32 + (1025 & 31)] = f2bf(im[(size_t)bt * FBINS + 1024]);
}

// ---------------- 1 / window_sumsquare --------------------------------------
__global__ void build_invws(float* __restrict__ iw) {
    int p = blockIdx.x * 256 + threadIdx.x;
    if (p >= TOTALP) return;
    int tmax = p >> 9;            if (tmax > TFRAMES - 1) tmax = TFRAMES - 1;
    int tmin = (p - 1536) >> 9;   if (tmin < 0) tmin = 0;
    float s = 0.0f;
    for (int t = tmin; t <= tmax; ++t) {
        int   a = p - (t << 9);
        float w = 0.5f - 0.5f * cospif((float)a * (1.0f / 1024.0f));
        s += w * w;
    }
    s = fmaxf(s, 1e-8f);
    iw[p] = 1.0f / s;
}

// ---------------- GEMM (bf16 MFMA, radix-2, depth-3 pipeline) + fused OLA ---
// 128x128 tile over (bt, a), a in [0,1024). accE/accO over even/odd K classes.
// Depth-3 LDS pipeline with counted vmcnt(4): stage ks+2 at top of iter ks,
// wait only for stage ks+1 at the end (one full iteration of latency cover).
// NO __syncthreads in the main loop (it would drain vmcnt to 0).
#define BM  128
#define BN  128
#define BK  32
#define TILE_A (BM * BK)
#define TILE_B (BN * BK)

#define WAITV(N) asm volatile("s_waitcnt vmcnt(" #N ")" ::: "memory")

__global__ __launch_bounds__(256) void gemm_ola(
    const unsigned short* __restrict__ X2,  // [KSTEPS][MROWS][32]
    const unsigned short* __restrict__ W2,  // [KSTEPS][NCOLS][32]
    const float*          __restrict__ iw,  // [TOTALP]
    float*                __restrict__ out) // [BATCH][OUTLEN]
{
    __shared__ __align__(16) unsigned short As[3 * TILE_A];
    __shared__ __align__(16) unsigned short Bs[3 * TILE_B];

    const int tid  = threadIdx.x;
    const int lane = tid & 63;
    const int w    = tid >> 6;
    const int wr   = w >> 1, wc = w & 1;
    const int l16  = lane & 15, lhi = lane >> 4;

    // XCD-grouping swizzle: bid = c + 8*(colTile + 8*ygrp); rowTile = ygrp*8+c
    const int bid     = blockIdx.x;
    const int c       = bid & 7;
    const int r2      = bid >> 3;
    const int colTile = r2 & 7;
    const int rowTile = ((r2 >> 3) << 3) + c;

    const int colBase = colTile * BN;    // a in [0,1024)
    const int rowBase = rowTile * BM;    // bt

    f32x4 accE[4][4], accO[4][4];
    #pragma unroll
    for (int i = 0; i < 4; ++i)
        #pragma unroll
        for (int j = 0; j < 4; ++j) {
            accE[i][j] = f32x4{0.f, 0.f, 0.f, 0.f};
            accO[i][j] = f32x4{0.f, 0.f, 0.f, 0.f};
        }

#define STAGE(slot, ks) do {                                                       \
    const unsigned short* aP = X2 + ((size_t)(ks) * MROWS + rowBase) * BK;         \
    const unsigned short* bP = W2 + ((size_t)(ks) * NCOLS + colBase) * BK;         \
    unsigned short* Al = As + (slot) * TILE_A;                                     \
    unsigned short* Bl = Bs + (slot) * TILE_B;                                     \
    __builtin_amdgcn_global_load_lds((gmem_void*)(aP + tid * 8),                   \
                                     (lds_void*)(Al + tid * 8),         16, 0, 0); \
    __builtin_amdgcn_global_load_lds((gmem_void*)(aP + (256 + tid) * 8),           \
                                     (lds_void*)(Al + (256 + tid) * 8), 16, 0, 0); \
    __builtin_amdgcn_global_load_lds((gmem_void*)(bP + tid * 8),                   \
                                     (lds_void*)(Bl + tid * 8),         16, 0, 0); \
    __builtin_amdgcn_global_load_lds((gmem_void*)(bP + (256 + tid) * 8),           \
                                     (lds_void*)(Bl + (256 + tid) * 8), 16, 0, 0); \
} while (0)

#define COMPUTE(slot, ACC) do {                                                    \
    const unsigned short* Ab = As + (slot) * TILE_A;                               \
    const unsigned short* Bb = Bs + (slot) * TILE_B;                               \
    bf16x8 af[4], bfr[4];                                                          \
    _Pragma("unroll")                                                              \
    for (int mi = 0; mi < 4; ++mi)                                                 \
        af[mi] = *(const bf16x8*)(Ab + (wr * 64 + mi * 16 + l16) * BK + lhi * 8);  \
    _Pragma("unroll")                                                              \
    for (int ni = 0; ni < 4; ++ni)                                                 \
        bfr[ni] = *(const bf16x8*)(Bb + (wc * 64 + ni * 16 + l16) * BK + lhi * 8); \
    _Pragma("unroll")                                                              \
    for (int mi = 0; mi < 4; ++mi)                                                 \
        _Pragma("unroll")                                                          \
        for (int ni = 0; ni < 4; ++ni)                                             \
            ACC[mi][ni] = __builtin_amdgcn_mfma_f32_16x16x32_bf16(                 \
                af[mi], bfr[ni], ACC[mi][ni], 0, 0, 0);                            \
} while (0)

    // prologue: fill slots 0,1; wait for slot 0 only (vmcnt 8 -> 4)
    STAGE(0, 0);
    STAGE(1, 1);
    WAITV(4);
    __builtin_amdgcn_s_barrier();

    int cur = 0;
    // ---- even-class K loop: ks = 0..32 -> accE ----
    #pragma unroll 3
    for (int ks = 0; ks < KS_E; ++ks) {
        int st = cur + 2; if (st >= 3) st -= 3;
        STAGE(st, ks + 2);
        COMPUTE(cur, accE);
        WAITV(4);                       // stage(ks+1) done; stage(ks+2) in flight
        __builtin_amdgcn_s_barrier();
        cur = (cur == 2) ? 0 : cur + 1;
    }
    // ---- odd-class K loop: ks = 33..62 -> accO ----
    #pragma unroll 3
    for (int ks = KS_E; ks < KSTEPS - 2; ++ks) {
        int st = cur + 2; if (st >= 3) st -= 3;
        STAGE(st, ks + 2);
        COMPUTE(cur, accO);
        WAITV(4);
        __builtin_amdgcn_s_barrier();
        cur = (cur == 2) ? 0 : cur + 1;
    }
    // ---- tail: ks = 63 (no more staging), ks = 64 ----
    COMPUTE(cur, accO);                 // ks=63, slot 0
    WAITV(0);                           // stage(64) done
    __builtin_amdgcn_s_barrier();
    cur = (cur == 2) ? 0 : cur + 1;
    COMPUTE(cur, accO);                 // ks=64, slot 1

    // ---- fused overlap-add epilogue ----
    #pragma unroll
    for (int ni = 0; ni < 4; ++ni) {
        const int a   = colBase + wc * 64 + ni * 16 + l16;
        const float win = 0.5f - 0.5f * cospif((float)a * (1.0f / 1024.0f));
        #pragma unroll
        for (int mi = 0; mi < 4; ++mi) {
            const int grBase = rowBase + wr * 64 + mi * 16 + lhi * 4;
            #pragma unroll
            for (int r = 0; r < 4; ++r) {
                const int row = grBase + r;          // bt
                const int t   = row & (TFRAMES - 1);
                const int b   = row >> 11;
                const int p0  = t * HOPSZ + a;
                const int n0  = p0 - (NFFT / 2);
                const float E = accE[mi][ni][r], O = accO[mi][ni][r];
                float* ob = out + (size_t)b * OUTLEN;
                if (n0 >= 0 && n0 < OUTLEN)
                    unsafeAtomicAdd(ob + n0, (E + O) * win * iw[p0]);
                const int n1 = n0 + 1024;
                if (n1 >= 0 && n1 < OUTLEN)
                    unsafeAtomicAdd(ob + n1, (E - O) * (1.0f - win) * iw[p0 + 1024]);
            }
        }
    }
}

// ---------------- launch -----------------------------------------------------
extern "C" void kernel_launch(void* const* d_in, const int* in_sizes, int n_in,
                              void* d_out, int out_size, void* d_ws, size_t ws_size,
                              hipStream_t stream) {
    const float* re = (const float*)d_in[0];
    const float* im = (const float*)d_in[1];
    float* out = (float*)d_out;

    char* ws = (char*)d_ws;
    unsigned short* X2   = (unsigned short*)(ws);                        // 65*16384*32*2 = 68,157,440 B
    unsigned short* W2   = (unsigned short*)(ws + 68157440);             // 65*1024*32*2  =  4,259,840 B
    float*          invw = (float*)        (ws + 68157440 + 4259840);    // 1050112*4     =  4,200,448 B

    hipMemsetAsync(d_out, 0, (size_t)out_size * sizeof(float), stream);

    build_w    <<<dim3(2, NCOLS), 256, 0, stream>>>(W2);
    conv_x     <<<dim3(MROWS),    256, 0, stream>>>(re, im, X2);
    build_invws<<<dim3(4102),     256, 0, stream>>>(invw);
    gemm_ola   <<<dim3((MROWS / BM) * (NCOLS / BN)), 256, 0, stream>>>(X2, W2, invw, out);
}

// Round 5
// 221.159 us; speedup vs baseline: 1.1292x; 1.1292x over previous
//
#include <hip/hip_runtime.h>

// ---------------- problem constants ----------------
#define NFFT    2048
#define HOPSZ   512
#define BATCH   8
#define TFRAMES 2048
#define FBINS   1025
#define OUTLEN  1048064           // HOP*(T-1)
#define TOTALP  1050112           // NFFT + HOP*(T-1)
#define MROWS   16384             // BATCH*TFRAMES
#define NCOLS   1024              // radix-2: a in [0,1024)
#define DSTEPS  33                // double K-steps; each covers one even + one odd 32-slice
// within-class packing (32-wide steps):
//   even class (1056 = 33*32): [Re even-bins 512 | Im even-bins 512 | Re1024 | Im1024 | 30 zeros]
//   odd  class (1056 = 33*32): [Re odd-bins 512 | Im odd-bins 512 | 32 zeros]
// X2 layout: [DSTEPS][2][MROWS][32] bf16 ; W2 layout: [DSTEPS][2][NCOLS][32] bf16

typedef float  f32x4  __attribute__((ext_vector_type(4)));
typedef __bf16 bf16x8 __attribute__((ext_vector_type(8)));

typedef __attribute__((address_space(3))) void       lds_void;
typedef const __attribute__((address_space(1))) void gmem_void;

__device__ __forceinline__ unsigned short f2bf(float f) {
    unsigned u = __float_as_uint(f);
    u += 0x7fffu + ((u >> 16) & 1u);       // round-to-nearest-even
    return (unsigned short)(u >> 16);
}

// ---------------- W2: packed bf16 IDFT weights (window factored out) --------
__global__ void build_w(unsigned short* __restrict__ W2) {
    int idx = blockIdx.x * 256 + threadIdx.x;     // 8-elem chunk, 264 total
    if (idx >= 264) return;
    int a  = blockIdx.y;                          // [0,1024)
    int k0 = idx * 8;                             // flat packed index [0,2112)
    int cls    = (k0 >= 1056) ? 1 : 0;
    int within = k0 - cls * 1056;
    unsigned short v[8];
    #pragma unroll
    for (int jj = 0; jj < 8; ++jj) {
        int wk = within + jj;
        int bin = 0; bool isSin = false; bool valid = true;
        if (cls == 0) {
            if      (wk < 512)  { bin = 2 * wk;          isSin = false; }
            else if (wk < 1024) { bin = 2 * (wk - 512);  isSin = true;  }
            else if (wk == 1024){ bin = 1024;            isSin = false; }
            else if (wk == 1025){ bin = 1024;            isSin = true;  }
            else valid = false;
        } else {
            if      (wk < 512)  { bin = 2 * wk + 1;         isSin = false; }
            else if (wk < 1024) { bin = 2 * (wk - 512) + 1; isSin = true;  }
            else valid = false;
        }
        float f = 0.0f;
        if (valid) {
            int   m = (bin * a) & 2047;
            float c = (bin == 0 || bin == 1024) ? 1.0f : 2.0f;
            float tr = isSin ? -sinpif((float)m * (1.0f / 1024.0f))
                             :  cospif((float)m * (1.0f / 1024.0f));
            f = c * tr * (1.0f / 2048.0f);
        }
        v[jj] = f2bf(f);
    }
    int j = within >> 5;                          // within-class step
    *(uint4*)(W2 + ((size_t)(j * 2 + cls) * NCOLS + a) * 32 + (within & 31)) = *(const uint4*)v;
}

// ---------------- X2: packed bf16 inputs ------------------------------------
__global__ void conv_x(const float* __restrict__ re, const float* __restrict__ im,
                       unsigned short* __restrict__ X2) {
    const int bt  = blockIdx.x;
    const int tid = threadIdx.x;
    const bool isIm = tid >= 128;
    const int  t8   = tid & 127;                  // bins [8*t8, 8*t8+8)
    const float* src = (isIm ? im : re) + (size_t)bt * FBINS;

    float f[8];
    #pragma unroll
    for (int j = 0; j < 8; ++j) f[j] = src[t8 * 8 + j];

    unsigned short ev[4], od[4];
    #pragma unroll
    for (int i = 0; i < 4; ++i) { ev[i] = f2bf(f[2 * i]); od[i] = f2bf(f[2 * i + 1]); }

    const int e0 = (isIm ? 512 : 0) + t8 * 4;     // within-even index (mult of 4)
    const int o0 = e0;                            // within-odd index
    *(uint2*)(X2 + ((size_t)((e0 >> 5) * 2 + 0) * MROWS + bt) * 32 + (e0 & 31)) = *(const uint2*)ev;
    *(uint2*)(X2 + ((size_t)((o0 >> 5) * 2 + 1) * MROWS + bt) * 32 + (o0 & 31)) = *(const uint2*)od;

    // extras: even step 32 holds [Re1024, Im1024, 30 zeros]; odd step 32 all zero
    if (tid < 30)
        X2[((size_t)(32 * 2 + 0) * MROWS + bt) * 32 + (2 + tid)] = 0;
    else if (tid == 30)
        X2[((size_t)(32 * 2 + 0) * MROWS + bt) * 32 + 0] = f2bf(re[(size_t)bt * FBINS + 1024]);
    else if (tid == 31)
        X2[((size_t)(32 * 2 + 0) * MROWS + bt) * 32 + 1] = f2bf(im[(size_t)bt * FBINS + 1024]);
    else if (tid < 96)   // 32..95 -> odd zero-step cols 0..31 (32..63) ; spare 64..95 no-op
        { if (tid < 64) X2[((size_t)(32 * 2 + 1) * MROWS + bt) * 32 + (tid - 32)] = 0; }
}

// ---------------- 1 / window_sumsquare --------------------------------------
__global__ void build_invws(float* __restrict__ iw) {
    int p = blockIdx.x * 256 + threadIdx.x;
    if (p >= TOTALP) return;
    int tmax = p >> 9;            if (tmax > TFRAMES - 1) tmax = TFRAMES - 1;
    int tmin = (p - 1536) >> 9;   if (tmin < 0) tmin = 0;
    float s = 0.0f;
    for (int t = tmin; t <= tmax; ++t) {
        int   a = p - (t << 9);
        float w = 0.5f - 0.5f * cospif((float)a * (1.0f / 1024.0f));
        s += w * w;
    }
    s = fmaxf(s, 1e-8f);
    iw[p] = 1.0f / s;
}

// ---------------- GEMM: wave-specialized radix-2 + fused OLA ----------------
// 128x128 (bt,a) tile, 8 waves: waves 0-3 accumulate EVEN class, 4-7 ODD,
// each wave one 64x64 tile (single acc set = 64 VGPRs). Depth-2 LDS pipeline,
// 32KB double-K stages via global_load_lds. Epilogue: E-waves -> LDS f32 buf,
// O-waves combine (E+O)*win, (E-O)*(1-win) and overlap-add atomically.
#define SLOT_SH  16384            // shorts per 32KB slot
#define EBSWZ(row, col) ((col) ^ ((((row) >> 2) & 7) << 2))

#define WAITV0 asm volatile("s_waitcnt vmcnt(0)" ::: "memory")

__global__ __launch_bounds__(512, 4) void gemm_ola(
    const unsigned short* __restrict__ X2,  // [DSTEPS][2][MROWS][32]
    const unsigned short* __restrict__ W2,  // [DSTEPS][2][NCOLS][32]
    const float*          __restrict__ iw,  // [TOTALP]
    float*                __restrict__ out) // [BATCH][OUTLEN]
{
    __shared__ __align__(16) unsigned char smem[65536];
    unsigned short* S = (unsigned short*)smem;

    const int tid  = threadIdx.x;
    const int lane = tid & 63;
    const int w    = tid >> 6;
    const bool isO = w >= 4;
    const int w2   = w & 3;
    const int wr   = w2 >> 1, wc = w2 & 1;
    const int l16  = lane & 15, lhi = lane >> 4;

    // XCD-grouping swizzle: bid = c + 8*(colTile + 8*ygrp); rowTile = ygrp*8+c
    const int bid     = blockIdx.x;
    const int c       = bid & 7;
    const int r2      = bid >> 3;
    const int colTile = r2 & 7;
    const int rowTile = ((r2 >> 3) << 3) + c;
    const int colBase = colTile * 128;   // a
    const int rowBase = rowTile * 128;   // bt

    f32x4 acc[4][4];
    #pragma unroll
    for (int i = 0; i < 4; ++i)
        #pragma unroll
        for (int j = 0; j < 4; ++j)
            acc[i][j] = f32x4{0.f, 0.f, 0.f, 0.f};

#define STAGE(slot, i) do {                                                        \
    const unsigned short* gA = X2 + ((size_t)(i) * 2 * MROWS + rowBase) * 32 + tid * 8; \
    const unsigned short* gB = W2 + ((size_t)(i) * 2 * NCOLS + colBase) * 32 + tid * 8; \
    unsigned short* L = S + (slot) * SLOT_SH + tid * 8;                            \
    __builtin_amdgcn_global_load_lds((gmem_void*)gA,                               \
                                     (lds_void*)(L),          16, 0, 0);           \
    __builtin_amdgcn_global_load_lds((gmem_void*)(gA + (size_t)MROWS * 32),        \
                                     (lds_void*)(L + 4096),   16, 0, 0);           \
    __builtin_amdgcn_global_load_lds((gmem_void*)gB,                               \
                                     (lds_void*)(L + 8192),   16, 0, 0);           \
    __builtin_amdgcn_global_load_lds((gmem_void*)(gB + (size_t)NCOLS * 32),        \
                                     (lds_void*)(L + 12288),  16, 0, 0);           \
} while (0)

#define COMPUTE(slot) do {                                                         \
    const unsigned short* Ab = S + (slot) * SLOT_SH + (isO ? 4096 : 0);            \
    const unsigned short* Bb = S + (slot) * SLOT_SH + 8192 + (isO ? 4096 : 0);     \
    bf16x8 af[4], bfr[4];                                                          \
    _Pragma("unroll")                                                              \
    for (int mi = 0; mi < 4; ++mi)                                                 \
        af[mi] = *(const bf16x8*)(Ab + (wr * 64 + mi * 16 + l16) * 32 + lhi * 8);  \
    _Pragma("unroll")                                                              \
    for (int ni = 0; ni < 4; ++ni)                                                 \
        bfr[ni] = *(const bf16x8*)(Bb + (wc * 64 + ni * 16 + l16) * 32 + lhi * 8); \
    _Pragma("unroll")                                                              \
    for (int mi = 0; mi < 4; ++mi)                                                 \
        _Pragma("unroll")                                                          \
        for (int ni = 0; ni < 4; ++ni)                                             \
            acc[mi][ni] = __builtin_amdgcn_mfma_f32_16x16x32_bf16(                 \
                af[mi], bfr[ni], acc[mi][ni], 0, 0, 0);                            \
} while (0)

    // prologue
    STAGE(0, 0);
    WAITV0;
    __builtin_amdgcn_s_barrier();

    #pragma unroll 2
    for (int i = 0; i < DSTEPS - 1; ++i) {
        STAGE((i & 1) ^ 1, i + 1);     // issue next double-stage FIRST
        COMPUTE(i & 1);                // compute current (hides load latency)
        WAITV0;
        __builtin_amdgcn_s_barrier();
    }
    COMPUTE((DSTEPS - 1) & 1);         // i=32, slot 0
    __syncthreads();                   // all ds_reads done before LDS reuse

    // ---- epilogue: E-waves publish accE via LDS, O-waves combine + OLA ----
    float* EB = (float*)smem;          // f32 [128][128], col-swizzled
    if (!isO) {
        #pragma unroll
        for (int mi = 0; mi < 4; ++mi)
            #pragma unroll
            for (int ni = 0; ni < 4; ++ni) {
                const int col = wc * 64 + ni * 16 + l16;
                #pragma unroll
                for (int r = 0; r < 4; ++r) {
                    const int row = wr * 64 + mi * 16 + lhi * 4 + r;
                    EB[row * 128 + EBSWZ(row, col)] = acc[mi][ni][r];
                }
            }
    }
    __syncthreads();
    if (isO) {
        #pragma unroll
        for (int ni = 0; ni < 4; ++ni) {
            const int lcol = wc * 64 + ni * 16 + l16;
            const int a    = colBase + lcol;
            const float win = 0.5f - 0.5f * cospif((float)a * (1.0f / 1024.0f));
            #pragma unroll
            for (int mi = 0; mi < 4; ++mi) {
                #pragma unroll
                for (int r = 0; r < 4; ++r) {
                    const int lrow = wr * 64 + mi * 16 + lhi * 4 + r;
                    const float E  = EB[lrow * 128 + EBSWZ(lrow, lcol)];
                    const float O  = acc[mi][ni][r];
                    const int row  = rowBase + lrow;        // bt
                    const int t    = row & (TFRAMES - 1);
                    const int b    = row >> 11;
                    const int p0   = t * HOPSZ + a;
                    const int n0   = p0 - (NFFT / 2);
                    float* ob = out + (size_t)b * OUTLEN;
                    if (n0 >= 0 && n0 < OUTLEN)
                        unsafeAtomicAdd(ob + n0, (E + O) * win * iw[p0]);
                    const int n1 = n0 + 1024;               // = p0 >= 0 always
                    if (n1 < OUTLEN)
                        unsafeAtomicAdd(ob + n1, (E - O) * (1.0f - win) * iw[p0 + 1024]);
                }
            }
        }
    }
}

// ---------------- launch -----------------------------------------------------
extern "C" void kernel_launch(void* const* d_in, const int* in_sizes, int n_in,
                              void* d_out, int out_size, void* d_ws, size_t ws_size,
                              hipStream_t stream) {
    const float* re = (const float*)d_in[0];
    const float* im = (const float*)d_in[1];
    float* out = (float*)d_out;

    char* ws = (char*)d_ws;
    unsigned short* X2   = (unsigned short*)(ws);                        // 33*2*16384*32*2 = 69,206,016 B
    unsigned short* W2   = (unsigned short*)(ws + 69206016);             // 33*2*1024*32*2  =  4,325,376 B
    float*          invw = (float*)        (ws + 69206016 + 4325376);    // 1050112*4       =  4,200,448 B

    hipMemsetAsync(d_out, 0, (size_t)out_size * sizeof(float), stream);

    build_w    <<<dim3(2, NCOLS), 256, 0, stream>>>(W2);
    conv_x     <<<dim3(MROWS),    256, 0, stream>>>(re, im, X2);
    build_invws<<<dim3(4102),     256, 0, stream>>>(invw);
    gemm_ola   <<<dim3((MROWS / 128) * (NCOLS / 128)), 512, 0, stream>>>(X2, W2, invw, out);
}

// Round 6
// 209.246 us; speedup vs baseline: 1.1935x; 1.0569x over previous
//
#include <hip/hip_runtime.h>

// ---------------- problem constants ----------------
#define NFFT    2048
#define HOPSZ   512
#define BATCH   8
#define TFRAMES 2048
#define FBINS   1025
#define OUTLEN  1048064           // HOP*(T-1)
#define TOTALP  1050112           // NFFT + HOP*(T-1)
#define MROWS   16384             // BATCH*TFRAMES
#define NCOLS   1024              // radix-2: a in [0,1024)
#define DSTEPS  33                // double K-steps (even 32 + odd 32 per step)
// A/B operand layout per double-step: [row][8 chunks of 8 bf16] = 128B rows.
// chunk c: 0-3 = even-class k (c*8..), 4-7 = odd-class k ((c-4)*8..).
// Stored at PHYSICAL chunk c ^ (row&7)  (XOR bank swizzle; global pre-swizzle
// so global_load_lds's linear LDS write lands the swizzled layout).

typedef float  f32x4  __attribute__((ext_vector_type(4)));
typedef __bf16 bf16x8 __attribute__((ext_vector_type(8)));

typedef __attribute__((address_space(3))) void       lds_void;
typedef const __attribute__((address_space(1))) void gmem_void;

__device__ __forceinline__ unsigned short f2bf(float f) {
    unsigned u = __float_as_uint(f);
    u += 0x7fffu + ((u >> 16) & 1u);       // round-to-nearest-even
    return (unsigned short)(u >> 16);
}

// ---------------- W2[i][a][8 chunks] : packed, swizzled bf16 IDFT weights ---
__global__ void build_w(unsigned short* __restrict__ W2) {
    int idx = blockIdx.x * 256 + threadIdx.x;     // logical 8-chunk, 264 total
    if (idx >= 264) return;
    int a  = blockIdx.y;                          // [0,1024)
    int k0 = idx * 8;                             // flat packed index [0,2112)
    int cls    = (k0 >= 1056) ? 1 : 0;
    int within = k0 - cls * 1056;
    unsigned short v[8];
    #pragma unroll
    for (int jj = 0; jj < 8; ++jj) {
        int wk = within + jj;
        int bin = 0; bool isSin = false; bool valid = true;
        if (cls == 0) {
            if      (wk < 512)  { bin = 2 * wk;          isSin = false; }
            else if (wk < 1024) { bin = 2 * (wk - 512);  isSin = true;  }
            else if (wk == 1024){ bin = 1024;            isSin = false; }
            else if (wk == 1025){ bin = 1024;            isSin = true;  }
            else valid = false;
        } else {
            if      (wk < 512)  { bin = 2 * wk + 1;         isSin = false; }
            else if (wk < 1024) { bin = 2 * (wk - 512) + 1; isSin = true;  }
            else valid = false;
        }
        float f = 0.0f;
        if (valid) {
            int   m = (bin * a) & 2047;
            float c = (bin == 0 || bin == 1024) ? 1.0f : 2.0f;
            float tr = isSin ? -sinpif((float)m * (1.0f / 1024.0f))
                             :  cospif((float)m * (1.0f / 1024.0f));
            f = c * tr * (1.0f / 2048.0f);
        }
        v[jj] = f2bf(f);
    }
    int i = within >> 5;                           // double-step
    int c = ((within >> 3) & 3) + cls * 4;         // logical chunk 0..7
    *(uint4*)(W2 + ((size_t)i * NCOLS + a) * 64 + ((c ^ (a & 7)) * 8)) = *(const uint4*)v;
}

// ---------------- X2[i][bt][8 chunks] : packed, swizzled bf16 inputs --------
__global__ void conv_x(const float* __restrict__ re, const float* __restrict__ im,
                       unsigned short* __restrict__ X2) {
    const int bt  = blockIdx.x;
    const int tid = threadIdx.x;
    const int sw  = bt & 7;
    const bool isIm = tid >= 128;
    const int  t8   = tid & 127;                  // bins [8*t8, 8*t8+8), all < 1024
    const float* src = (isIm ? im : re) + (size_t)bt * FBINS;

    float f[8];
    #pragma unroll
    for (int j = 0; j < 8; ++j) f[j] = src[t8 * 8 + j];

    unsigned short ev[4], od[4];
    #pragma unroll
    for (int i = 0; i < 4; ++i) { ev[i] = f2bf(f[2 * i]); od[i] = f2bf(f[2 * i + 1]); }

    const int we = (isIm ? 512 : 0) + t8 * 4;     // within-even base (mult of 4)
    const int i0 = we >> 5;                        // double-step (even/odd share it)
    const int ce = (we >> 3) & 3;                  // logical chunk (even class)
    const int h  = (we >> 2) & 1;                  // half-chunk
    const size_t rowb = ((size_t)i0 * MROWS + bt) * 64;
    *(uint2*)(X2 + rowb + ((ce       ^ sw) * 8) + h * 4) = *(const uint2*)ev;
    *(uint2*)(X2 + rowb + (((ce + 4) ^ sw) * 8) + h * 4) = *(const uint2*)od;

    // step 32: logical chunks 0-7 = [Re1024, Im1024, 62 zeros]
    if (tid >= 32 && tid < 96) {
        const int j = tid - 32;                    // 0..63
        const int c = j >> 3, e = j & 7;
        float val = 0.0f;
        if (j == 0)      val = re[(size_t)bt * FBINS + 1024];
        else if (j == 1) val = im[(size_t)bt * FBINS + 1024];
        X2[((size_t)32 * MROWS + bt) * 64 + ((c ^ sw) * 8) + e] = f2bf(val);
    }
}

// ---------------- 1 / window_sumsquare --------------------------------------
__global__ void build_invws(float* __restrict__ iw) {
    int p = blockIdx.x * 256 + threadIdx.x;
    if (p >= TOTALP) return;
    int tmax = p >> 9;            if (tmax > TFRAMES - 1) tmax = TFRAMES - 1;
    int tmin = (p - 1536) >> 9;   if (tmin < 0) tmin = 0;
    float s = 0.0f;
    for (int t = tmin; t <= tmax; ++t) {
        int   a = p - (t << 9);
        float w = 0.5f - 0.5f * cospif((float)a * (1.0f / 1024.0f));
        s += w * w;
    }
    s = fmaxf(s, 1e-8f);
    iw[p] = 1.0f / s;
}

// ---------------- GEMM: wave-specialized radix-2, counted vmcnt, swizzled ---
// 128x128 (bt,a) tile, 8 waves: 0-3 EVEN class, 4-7 ODD; each wave 64x64.
// 2 LDS slots x 32KB (A 16KB + B 16KB). Loop: COMPUTE(cur) -> barrier ->
// STAGE(cur, i+2) -> vmcnt(4) [waits stage(i+1), issued a FULL iteration ago]
// -> barrier. Never drains vmcnt to 0 in the loop.
#define SLOT_SH  16384            // shorts per 32KB slot
#define EBSWZ(row, col) ((col) ^ ((((row) >> 2) & 7) << 2))

#define WAITV(N) asm volatile("s_waitcnt vmcnt(" #N ")" ::: "memory")

__global__ __launch_bounds__(512, 4) void gemm_ola(
    const unsigned short* __restrict__ X2,  // [DSTEPS][MROWS][64]
    const unsigned short* __restrict__ W2,  // [DSTEPS][NCOLS][64]
    const float*          __restrict__ iw,  // [TOTALP]
    float*                __restrict__ out) // [BATCH][OUTLEN]
{
    __shared__ __align__(16) unsigned char smem[65536];
    unsigned short* S = (unsigned short*)smem;

    const int tid  = threadIdx.x;
    const int lane = tid & 63;
    const int w    = tid >> 6;
    const bool isO = w >= 4;
    const int w2   = w & 3;
    const int wr   = w2 >> 1, wc = w2 & 1;
    const int l16  = lane & 15, lhi = lane >> 4;
    const int cA   = (isO ? 4 : 0);               // logical chunk base for class

    // XCD-grouping swizzle: bid = c + 8*(colTile + 8*ygrp); rowTile = ygrp*8+c
    const int bid     = blockIdx.x;
    const int c       = bid & 7;
    const int r2      = bid >> 3;
    const int colTile = r2 & 7;
    const int rowTile = ((r2 >> 3) << 3) + c;
    const int colBase = colTile * 128;   // a
    const int rowBase = rowTile * 128;   // bt

    f32x4 acc[4][4];
    #pragma unroll
    for (int i = 0; i < 4; ++i)
        #pragma unroll
        for (int j = 0; j < 4; ++j)
            acc[i][j] = f32x4{0.f, 0.f, 0.f, 0.f};

#define STAGE(slot, i) do {                                                        \
    const unsigned short* gA = X2 + ((size_t)(i) * MROWS + rowBase) * 64 + tid * 8;\
    const unsigned short* gB = W2 + ((size_t)(i) * NCOLS + colBase) * 64 + tid * 8;\
    unsigned short* L = S + (slot) * SLOT_SH + tid * 8;                            \
    __builtin_amdgcn_global_load_lds((gmem_void*)gA,                               \
                                     (lds_void*)(L),          16, 0, 0);           \
    __builtin_amdgcn_global_load_lds((gmem_void*)(gA + 4096),                      \
                                     (lds_void*)(L + 4096),   16, 0, 0);           \
    __builtin_amdgcn_global_load_lds((gmem_void*)gB,                               \
                                     (lds_void*)(L + 8192),   16, 0, 0);           \
    __builtin_amdgcn_global_load_lds((gmem_void*)(gB + 4096),                      \
                                     (lds_void*)(L + 12288),  16, 0, 0);           \
} while (0)

#define COMPUTE(slot) do {                                                         \
    const unsigned short* Ab = S + (slot) * SLOT_SH;                               \
    const unsigned short* Bb = S + (slot) * SLOT_SH + 8192;                        \
    bf16x8 af[4], bfr[4];                                                          \
    _Pragma("unroll")                                                              \
    for (int mi = 0; mi < 4; ++mi) {                                               \
        const int row = wr * 64 + mi * 16 + l16;                                   \
        af[mi] = *(const bf16x8*)(Ab + row * 64 + (((lhi + cA) ^ (row & 7)) * 8)); \
    }                                                                              \
    _Pragma("unroll")                                                              \
    for (int ni = 0; ni < 4; ++ni) {                                               \
        const int col = wc * 64 + ni * 16 + l16;                                   \
        bfr[ni] = *(const bf16x8*)(Bb + col * 64 + (((lhi + cA) ^ (col & 7)) * 8));\
    }                                                                              \
    _Pragma("unroll")                                                              \
    for (int mi = 0; mi < 4; ++mi)                                                 \
        _Pragma("unroll")                                                          \
        for (int ni = 0; ni < 4; ++ni)                                             \
            acc[mi][ni] = __builtin_amdgcn_mfma_f32_16x16x32_bf16(                 \
                af[mi], bfr[ni], acc[mi][ni], 0, 0, 0);                            \
} while (0)

    // prologue: fill both slots; wait for slot 0 only
    STAGE(0, 0);
    STAGE(1, 1);
    WAITV(4);
    __builtin_amdgcn_s_barrier();

    #pragma unroll 2
    for (int i = 0; i < DSTEPS - 2; ++i) {        // i = 0..30
        COMPUTE(i & 1);
        __builtin_amdgcn_s_barrier();             // all waves done reading slot i&1
        STAGE(i & 1, i + 2);                      // refill with step i+2
        WAITV(4);                                 // stage(i+1) landed (issued @ i-1)
        __builtin_amdgcn_s_barrier();
    }
    COMPUTE(1);                                   // step 31 (slot 1)
    WAITV(0);                                     // stage(32) landed
    __builtin_amdgcn_s_barrier();
    COMPUTE(0);                                   // step 32 (slot 0)
    __syncthreads();                              // before LDS reuse for EB

    // ---- epilogue: E-waves publish accE via LDS, O-waves combine + OLA ----
    float* EB = (float*)smem;          // f32 [128][128], col-swizzled
    if (!isO) {
        #pragma unroll
        for (int mi = 0; mi < 4; ++mi)
            #pragma unroll
            for (int ni = 0; ni < 4; ++ni) {
                const int col = wc * 64 + ni * 16 + l16;
                #pragma unroll
                for (int r = 0; r < 4; ++r) {
                    const int row = wr * 64 + mi * 16 + lhi * 4 + r;
                    EB[row * 128 + EBSWZ(row, col)] = acc[mi][ni][r];
                }
            }
    }
    __syncthreads();
    if (isO) {
        #pragma unroll
        for (int ni = 0; ni < 4; ++ni) {
            const int lcol = wc * 64 + ni * 16 + l16;
            const int a    = colBase + lcol;
            const float win = 0.5f - 0.5f * cospif((float)a * (1.0f / 1024.0f));
            #pragma unroll
            for (int mi = 0; mi < 4; ++mi) {
                #pragma unroll
                for (int r = 0; r < 4; ++r) {
                    const int lrow = wr * 64 + mi * 16 + lhi * 4 + r;
                    const float E  = EB[lrow * 128 + EBSWZ(lrow, lcol)];
                    const float O  = acc[mi][ni][r];
                    const int row  = rowBase + lrow;        // bt
                    const int t    = row & (TFRAMES - 1);
                    const int b    = row >> 11;
                    const int p0   = t * HOPSZ + a;
                    const int n0   = p0 - (NFFT / 2);
                    float* ob = out + (size_t)b * OUTLEN;
                    if (n0 >= 0 && n0 < OUTLEN)
                        unsafeAtomicAdd(ob + n0, (E + O) * win * iw[p0]);
                    const int n1 = n0 + 1024;
                    if (n1 < OUTLEN)
                        unsafeAtomicAdd(ob + n1, (E - O) * (1.0f - win) * iw[p0 + 1024]);
                }
            }
        }
    }
}

// ---------------- launch -----------------------------------------------------
extern "C" void kernel_launch(void* const* d_in, const int* in_sizes, int n_in,
                              void* d_out, int out_size, void* d_ws, size_t ws_size,
                              hipStream_t stream) {
    const float* re = (const float*)d_in[0];
    const float* im = (const float*)d_in[1];
    float* out = (float*)d_out;

    char* ws = (char*)d_ws;
    unsigned short* X2   = (unsigned short*)(ws);                        // 33*16384*64*2 = 69,206,016 B
    unsigned short* W2   = (unsigned short*)(ws + 69206016);             // 33*1024*64*2  =  4,325,376 B
    float*          invw = (float*)        (ws + 69206016 + 4325376);    // 1050112*4     =  4,200,448 B

    hipMemsetAsync(d_out, 0, (size_t)out_size * sizeof(float), stream);

    build_w    <<<dim3(2, NCOLS), 256, 0, stream>>>(W2);
    conv_x     <<<dim3(MROWS),    256, 0, stream>>>(re, im, X2);
    build_invws<<<dim3(4102),     256, 0, stream>>>(invw);
    gemm_ola   <<<dim3((MROWS / 128) * (NCOLS / 128)), 512, 0, stream>>>(X2, W2, invw, out);
}

// Round 7
// 160.002 us; speedup vs baseline: 1.5608x; 1.3078x over previous
//
#include <hip/hip_runtime.h>

// ---------------- problem constants ----------------
#define NFFT    2048
#define HOPSZ   512
#define BATCH   8
#define TFRAMES 2048
#define FBINS   1025
#define OUTLEN  1048064           // HOP*(T-1)
#define TOTALP  1050112           // NFFT + HOP*(T-1)
#define MROWS   16384             // BATCH*TFRAMES
#define NCOLS   1024              // radix-2: a in [0,1024)
#define DSTEPS  32                // double K-steps: 32 even + 32 odd k per step
// Per double-step operand rows: [row][8 chunks of 8 bf16] = 128B.
// Logical chunk 0-3 = even-class k (c*8+e), 4-7 = odd-class k.
// Physical chunk = logical ^ (row&7)  (XOR bank swizzle).
// Bin 1024 handled as rank-1 epilogue term (im*sin(pi a) == 0).

typedef float  f32x4  __attribute__((ext_vector_type(4)));
typedef __bf16 bf16x8 __attribute__((ext_vector_type(8)));
typedef unsigned short u16x8 __attribute__((ext_vector_type(8)));

typedef __attribute__((address_space(3))) void       lds_void;
typedef const __attribute__((address_space(1))) void gmem_void;

__device__ __forceinline__ unsigned short f2bf(float f) {
    unsigned u = __float_as_uint(f);
    u += 0x7fffu + ((u >> 16) & 1u);       // round-to-nearest-even
    return (unsigned short)(u >> 16);
}
__device__ __forceinline__ float bf2f(unsigned short h) {
    return __uint_as_float(((unsigned)h) << 16);
}

// ---------------- W2[s][a][8 chunks]: packed, swizzled bf16 IDFT weights ----
// (no window, no bin 1024)
__global__ void build_w(unsigned short* __restrict__ W2) {
    const int a = blockIdx.x;              // [0,1024)
    const int t = threadIdx.x;             // 256
    const int s   = t >> 3;                // double-step 0..31
    const int c   = t & 7;                 // logical chunk
    const int cls = c >> 2;                // 0 even bins, 1 odd bins
    const int kc  = c & 3;
    unsigned short v[8];
    #pragma unroll
    for (int e = 0; e < 8; ++e) {
        int k = s * 32 + kc * 8 + e;       // within-class [0,1024)
        int bin; bool isSin;
        if (k < 512) { bin = 2 * k + cls;         isSin = false; }
        else         { bin = 2 * (k - 512) + cls; isSin = true;  }
        float coef = (bin == 0) ? 1.0f : 2.0f;
        int   m  = (bin * a) & 2047;
        float tr = isSin ? -sinpif((float)m * (1.0f / 1024.0f))
                         :  cospif((float)m * (1.0f / 1024.0f));
        v[e] = f2bf(coef * tr * (1.0f / 2048.0f));
    }
    *(uint4*)(W2 + ((size_t)s * NCOLS + a) * 64 + ((c ^ (a & 7)) * 8)) = *(const uint4*)v;
}

// ---------------- win^2 table (2048 f32) ------------------------------------
__global__ void build_tabs(float* __restrict__ win2) {
    int p = blockIdx.x * 256 + threadIdx.x;
    if (p < 2048) {
        float w = 0.5f - 0.5f * cospif((float)p * (1.0f / 1024.0f));
        win2[p] = w * w;
    }
}

// ---------------- GEMM: radix-2 wave-specialized, reg-staged A, plane OLA ---
// 128x128 (bt,a) tile, 8 waves: 0-3 EVEN class, 4-7 ODD; each wave 64x64.
// A staged from re/im f32 (16 scalar loads -> cvt -> 2 ds_write_b128, swizzled);
// B staged via global_load_lds from pre-swizzled W2. Depth-2 LDS pipeline.
// Epilogue: E-waves -> LDS f32 buf; O-waves combine (E+-O)*win and store bf16
// into 4 disjoint OLA planes Y[b][t&3][p] (exact tiling, NO atomics).
#define SLOT_SH  16384            // shorts per 32KB slot (A 16KB + B 16KB)
#define EBSWZ(row, col) ((col) ^ ((((row) >> 2) & 7) << 2))

#define WAITV(N) asm volatile("s_waitcnt vmcnt(" #N ")" ::: "memory")
#define WAITL0   asm volatile("s_waitcnt lgkmcnt(0)" ::: "memory")

__global__ __launch_bounds__(512, 2) void gemm_planes(
    const float* __restrict__ re, const float* __restrict__ im,
    const unsigned short* __restrict__ W2,   // [DSTEPS][NCOLS][64]
    unsigned short* __restrict__ Y)          // [BATCH][4][TOTALP] bf16
{
    __shared__ __align__(16) unsigned char smem[65536];
    unsigned short* S = (unsigned short*)smem;

    const int tid  = threadIdx.x;
    const int lane = tid & 63;
    const int w    = tid >> 6;
    const bool isO = w >= 4;
    const int w2   = w & 3;
    const int wr   = w2 >> 1, wc = w2 & 1;
    const int l16  = lane & 15, lhi = lane >> 4;
    const int cA   = (isO ? 4 : 0);          // logical chunk base for class

    // XCD-grouping swizzle: bid = cx + 8*(colTile + 8*ygrp); rowTile = ygrp*8+cx
    const int bid     = blockIdx.x;
    const int cx      = bid & 7;
    const int r2      = bid >> 3;
    const int colTile = r2 & 7;
    const int rowTile = ((r2 >> 3) << 3) + cx;
    const int colBase = colTile * 128;       // a
    const int rowBase = rowTile * 128;       // bt

    // A-staging thread coords: row 0..127, logical even-chunk 0..3
    const int arow = tid >> 2;
    const int ace  = tid & 3;
    const size_t asrc_row = (size_t)(rowBase + arow) * FBINS;

    f32x4 acc[4][4];
    #pragma unroll
    for (int i = 0; i < 4; ++i)
        #pragma unroll
        for (int j = 0; j < 4; ++j)
            acc[i][j] = f32x4{0.f, 0.f, 0.f, 0.f};

    float rA[16];

// issue 16 contiguous scalar f32 loads for double-step i (covers this thread's
// 8 even + 8 odd values, interleaved as pairs)
#define ISSUEA(i) do {                                                          \
    const float* _s = ((i) < 16 ? re : im) + asrc_row                           \
                      + (((i) < 16) ? ((i) * 64) : ((i) * 64 - 1024))           \
                      + ace * 16;                                               \
    _Pragma("unroll")                                                           \
    for (int _j = 0; _j < 16; ++_j) rA[_j] = _s[_j];                            \
} while (0)

// convert rA -> bf16 and write swizzled into slot's A region
#define CVTDSW(slot) do {                                                       \
    unsigned short* _L = S + (slot) * SLOT_SH + arow * 64;                      \
    u16x8 _ve, _vo;                                                             \
    _Pragma("unroll")                                                           \
    for (int _j = 0; _j < 8; ++_j) {                                            \
        _ve[_j] = f2bf(rA[2 * _j]);                                             \
        _vo[_j] = f2bf(rA[2 * _j + 1]);                                         \
    }                                                                           \
    *(u16x8*)(_L + ((ace       ^ (arow & 7)) * 8)) = _ve;                       \
    *(u16x8*)(_L + (((ace + 4) ^ (arow & 7)) * 8)) = _vo;                       \
} while (0)

#define ISSUEB(slot, i) do {                                                    \
    const unsigned short* _gB = W2 + ((size_t)(i) * NCOLS + colBase) * 64       \
                                + tid * 8;                                      \
    unsigned short* _LB = S + (slot) * SLOT_SH + 8192 + tid * 8;                \
    __builtin_amdgcn_global_load_lds((gmem_void*)_gB,                           \
                                     (lds_void*)_LB,          16, 0, 0);        \
    __builtin_amdgcn_global_load_lds((gmem_void*)(_gB + 4096),                  \
                                     (lds_void*)(_LB + 4096), 16, 0, 0);        \
} while (0)

#define COMPUTE(slot) do {                                                      \
    const unsigned short* Ab = S + (slot) * SLOT_SH;                            \
    const unsigned short* Bb = S + (slot) * SLOT_SH + 8192;                     \
    bf16x8 af[4], bfr[4];                                                       \
    _Pragma("unroll")                                                           \
    for (int mi = 0; mi < 4; ++mi) {                                            \
        const int row = wr * 64 + mi * 16 + l16;                                \
        af[mi] = *(const bf16x8*)(Ab + row * 64 + (((lhi + cA) ^ (row & 7)) * 8)); \
    }                                                                           \
    _Pragma("unroll")                                                           \
    for (int ni = 0; ni < 4; ++ni) {                                            \
        const int col = wc * 64 + ni * 16 + l16;                                \
        bfr[ni] = *(const bf16x8*)(Bb + col * 64 + (((lhi + cA) ^ (col & 7)) * 8)); \
    }                                                                           \
    _Pragma("unroll")                                                           \
    for (int mi = 0; mi < 4; ++mi)                                              \
        _Pragma("unroll")                                                       \
        for (int ni = 0; ni < 4; ++ni)                                          \
            acc[mi][ni] = __builtin_amdgcn_mfma_f32_16x16x32_bf16(              \
                af[mi], bfr[ni], acc[mi][ni], 0, 0, 0);                         \
} while (0)

    // ---- prologue: fill slots 0 (step 0) and 1 (step 1) ----
    ISSUEA(0);
    ISSUEB(0, 0);
    WAITV(2);                                 // A(0) landed (B(0) may linger)
    CVTDSW(0);
    ISSUEA(1);
    ISSUEB(1, 1);
    WAITV(2);                                 // B(0)+A(1) landed (B(1) in flight)
    CVTDSW(1);
    WAITL0;
    __builtin_amdgcn_s_barrier();

    // ---- main loop: compute step i from slot i&1, stage step i+2 ----
    #pragma unroll 2
    for (int i = 0; i < DSTEPS - 2; ++i) {    // i = 0..29
        ISSUEA(i + 2);
        COMPUTE(i & 1);
        __builtin_amdgcn_s_barrier();         // all waves done reading slot i&1
        WAITV(0);                             // rA(i+2) and B(i+1) landed
        CVTDSW(i & 1);                        // step i+2 -> slot i&1
        ISSUEB(i & 1, i + 2);
        WAITL0;                               // ds_writes visible
        __builtin_amdgcn_s_barrier();
    }
    COMPUTE(0);                               // step 30
    WAITV(0);                                 // B(31) landed
    __builtin_amdgcn_s_barrier();
    COMPUTE(1);                               // step 31
    __syncthreads();                          // before LDS reuse for EB

    // ---- epilogue: E-waves publish via LDS; O-waves combine + plane store ----
    float* EB = (float*)smem;                 // f32 [128][128], col-swizzled
    if (!isO) {
        #pragma unroll
        for (int mi = 0; mi < 4; ++mi)
            #pragma unroll
            for (int ni = 0; ni < 4; ++ni) {
                const int col = wc * 64 + ni * 16 + l16;
                #pragma unroll
                for (int r = 0; r < 4; ++r) {
                    const int row = wr * 64 + mi * 16 + lhi * 4 + r;
                    EB[row * 128 + EBSWZ(row, col)] = acc[mi][ni][r];
                }
            }
    }
    __syncthreads();
    if (isO) {
        const float sgn = (l16 & 1) ? -1.0f : 1.0f;   // (-1)^a, a parity = l16&1
        #pragma unroll
        for (int mi = 0; mi < 4; ++mi) {
            #pragma unroll
            for (int r = 0; r < 4; ++r) {
                const int lrow = wr * 64 + mi * 16 + lhi * 4 + r;
                const int row  = rowBase + lrow;          // bt
                const int t    = row & (TFRAMES - 1);
                const int b    = row >> 11;
                const float rk1 = re[(size_t)row * FBINS + 1024] * sgn
                                  * (1.0f / 2048.0f);
                unsigned short* Yb = Y + ((size_t)(b * 4 + (t & 3))) * TOTALP
                                       + t * HOPSZ;
                #pragma unroll
                for (int ni = 0; ni < 4; ++ni) {
                    const int lcol = wc * 64 + ni * 16 + l16;
                    const int a    = colBase + lcol;
                    const float win = 0.5f - 0.5f * cospif((float)a * (1.0f / 1024.0f));
                    const float E = EB[lrow * 128 + EBSWZ(lrow, lcol)] + rk1;
                    const float O = acc[mi][ni][r];
                    Yb[a]        = f2bf((E + O) * win);
                    Yb[a + 1024] = f2bf((E - O) * (1.0f - win));
                }
            }
        }
    }
}

// ---------------- final pass: gather 4 planes, divide by window-sumsquare ---
__global__ __launch_bounds__(256) void final_pass(
    const unsigned short* __restrict__ Y,    // [BATCH][4][TOTALP]
    const float*          __restrict__ win2, // [2048]
    float*                __restrict__ out)  // [BATCH][OUTLEN]
{
    const int tx = blockIdx.x * 256 + threadIdx.x;
    if (tx >= OUTLEN / 8) return;
    const int b  = blockIdx.y;
    const int n0 = tx * 8;
    const int p0 = n0 + 1024;
    int tmin = (p0 - 1536) >> 9;  if (tmin < 0) tmin = 0;
    int tmax = p0 >> 9;           if (tmax > TFRAMES - 1) tmax = TFRAMES - 1;

    float acc[8], ws[8];
    #pragma unroll
    for (int j = 0; j < 8; ++j) { acc[j] = 0.0f; ws[j] = 0.0f; }

    for (int t = tmin; t <= tmax; ++t) {
        const int a0 = p0 - t * HOPSZ;        // 8-run fully inside [0,2048)
        const uint4 pv = *(const uint4*)(Y + ((size_t)(b * 4 + (t & 3))) * TOTALP + p0);
        const unsigned pw[4] = {pv.x, pv.y, pv.z, pv.w};
        const float4 w0 = *(const float4*)(win2 + a0);
        const float4 w1 = *(const float4*)(win2 + a0 + 4);
        #pragma unroll
        for (int j = 0; j < 4; ++j) {
            acc[2 * j]     += bf2f((unsigned short)(pw[j] & 0xffffu));
            acc[2 * j + 1] += bf2f((unsigned short)(pw[j] >> 16));
        }
        ws[0] += w0.x; ws[1] += w0.y; ws[2] += w0.z; ws[3] += w0.w;
        ws[4] += w1.x; ws[5] += w1.y; ws[6] += w1.z; ws[7] += w1.w;
    }
    float r[8];
    #pragma unroll
    for (int j = 0; j < 8; ++j) r[j] = acc[j] / fmaxf(ws[j], 1e-8f);
    float4* o = (float4*)(out + (size_t)b * OUTLEN + n0);
    o[0] = float4{r[0], r[1], r[2], r[3]};
    o[1] = float4{r[4], r[5], r[6], r[7]};
}

// ---------------- launch -----------------------------------------------------
extern "C" void kernel_launch(void* const* d_in, const int* in_sizes, int n_in,
                              void* d_out, int out_size, void* d_ws, size_t ws_size,
                              hipStream_t stream) {
    const float* re = (const float*)d_in[0];
    const float* im = (const float*)d_in[1];
    float* out = (float*)d_out;

    char* ws = (char*)d_ws;
    unsigned short* W2   = (unsigned short*)(ws);                 // 32*1024*64*2 = 4,194,304 B
    unsigned short* Y    = (unsigned short*)(ws + 4194304);       // 8*4*1050112*2 = 67,207,168 B
    float*          win2 = (float*)        (ws + 4194304 + 67207168); // 8,192 B

    build_w   <<<dim3(NCOLS), 256, 0, stream>>>(W2);
    build_tabs<<<dim3(8),     256, 0, stream>>>(win2);
    gemm_planes<<<dim3((MROWS / 128) * (NCOLS / 128)), 512, 0, stream>>>(re, im, W2, Y);
    final_pass<<<dim3(512, BATCH), 256, 0, stream>>>(Y, win2, out);
}

// Round 8
// 97.929 us; speedup vs baseline: 2.5501x; 1.6339x over previous
//
#include <hip/hip_runtime.h>

// ---------------- problem constants ----------------
#define NFFT    2048
#define HOPSZ   512
#define BATCH   8
#define TFRAMES 2048
#define FBINS   1025
#define OUTLEN  1048064           // HOP*(T-1)
#define TOTALP  1050112           // NFFT + HOP*(T-1)
#define MROWS   16384             // BATCH*TFRAMES

__device__ __forceinline__ unsigned short f2bf(float f) {
    unsigned u = __float_as_uint(f);
    u += 0x7fffu + ((u >> 16) & 1u);       // round-to-nearest-even
    return (unsigned short)(u >> 16);
}
__device__ __forceinline__ float bf2f(unsigned short h) {
    return __uint_as_float(((unsigned)h) << 16);
}

// ---------------- win^2 table (2048 f32) ------------------------------------
__global__ void build_tabs(float* __restrict__ win2) {
    int p = blockIdx.x * 256 + threadIdx.x;
    if (p < 2048) {
        float w = 0.5f - 0.5f * cospif((float)p * (1.0f / 1024.0f));
        win2[p] = w * w;
    }
}

// ---------------- per-frame inverse real FFT + window + plane store ---------
// One 256-thread block per frame. 1024-pt complex Stockham radix-2 iFFT
// (DIF autosort, e^{+i} kernel, verified N=2/4/8), via the irfft packing:
//   Z[m] = (X[m]+conj(X[1024-m])) + i*e^{+i pi m/1024}*(X[m]-conj(X[1024-m]))
//   z = (1/1024) IDFT_1024(Z);  x[2n] = Re z[n]/2, x[2n+1] = Im z[n]/2.
// im[0], im[1024] contribute exactly 0 (matches reference mirror).
// Output: x[a]*win[a] stored bf16 into disjoint OLA plane Y[b][t&3][t*512+a].
__global__ __launch_bounds__(256) void fft_frames(
    const float* __restrict__ re, const float* __restrict__ im,
    unsigned short* __restrict__ Y)          // [BATCH][4][TOTALP] bf16
{
    __shared__ float2 buf[2048];             // ping-pong halves [0..1023],[1024..2047]
    __shared__ float2 tw[512];               // tw[p] = e^{+i pi p/512}

    const int u     = threadIdx.x;
    const int frame = blockIdx.x;
    const int b     = frame >> 11;
    const int t     = frame & (TFRAMES - 1);
    const float* rr = re + (size_t)frame * FBINS;
    const float* ii = im + (size_t)frame * FBINS;

    // twiddle table
    #pragma unroll
    for (int g = 0; g < 2; ++g) {
        int p = u + 256 * g;
        tw[p] = float2{cospif((float)p * (1.0f / 512.0f)),
                       sinpif((float)p * (1.0f / 512.0f))};
    }

    // pack Z into buf[0..1023]
    #pragma unroll
    for (int h = 0; h < 4; ++h) {
        int m = u + 256 * h;
        float Zr, Zi;
        if (m == 0) {
            float r0 = rr[0], rN = rr[1024];
            Zr = r0 + rN; Zi = r0 - rN;
        } else {
            float Xr = rr[m],        Xi =  ii[m];
            float Cr = rr[1024 - m], Ci = -ii[1024 - m];
            float Er = Xr + Cr, Ei = Xi + Ci;
            float Or = Xr - Cr, Oi = Xi - Ci;
            float Wr = cospif((float)m * (1.0f / 1024.0f));
            float Wi = sinpif((float)m * (1.0f / 1024.0f));
            Zr = Er - (Wr * Oi + Wi * Or);
            Zi = Ei + (Wr * Or - Wi * Oi);
        }
        buf[m] = float2{Zr, Zi};
    }
    __syncthreads();

    // 10 Stockham radix-2 stages: src half -> dst half, autosorted output
    #pragma unroll
    for (int s = 0; s < 10; ++s) {
        const int m    = 1 << s;             // 1..512
        const int srcO = (s & 1) ? 1024 : 0;
        const int dstO = 1024 - srcO;
        #pragma unroll
        for (int h = 0; h < 2; ++h) {
            const int bf = u + 256 * h;      // butterfly index 0..511
            const int p  = bf & ~(m - 1);    // = j*m, twiddle index
            float2 a = buf[srcO + bf];
            float2 c = buf[srcO + bf + 512];
            float2 w = tw[p];
            float dr = a.x - c.x, di = a.y - c.y;
            buf[dstO + bf + p]     = float2{a.x + c.x, a.y + c.y};
            buf[dstO + bf + p + m] = float2{w.x * dr - w.y * di,
                                            w.x * di + w.y * dr};
        }
        __syncthreads();
    }
    // result z[n] in buf[0..1023]

    // unpack + window + bf16 plane store (coalesced 4B stores)
    unsigned short* Yb = Y + ((size_t)(b * 4 + (t & 3))) * TOTALP + t * HOPSZ;
    const float sc = 1.0f / 2048.0f;
    #pragma unroll
    for (int h = 0; h < 4; ++h) {
        int n = u + 256 * h;
        float2 z = buf[n];
        float w0 = 0.5f - 0.5f * cospif((float)(2 * n)     * (1.0f / 1024.0f));
        float w1 = 0.5f - 0.5f * cospif((float)(2 * n + 1) * (1.0f / 1024.0f));
        unsigned pack = ((unsigned)f2bf(z.y * sc * w1) << 16)
                      |  (unsigned)f2bf(z.x * sc * w0);
        *(unsigned*)(Yb + 2 * n) = pack;
    }
}

// ---------------- final pass: gather 4 planes, divide by window-sumsquare ---
__global__ __launch_bounds__(256) void final_pass(
    const unsigned short* __restrict__ Y,    // [BATCH][4][TOTALP]
    const float*          __restrict__ win2, // [2048]
    float*                __restrict__ out)  // [BATCH][OUTLEN]
{
    const int tx = blockIdx.x * 256 + threadIdx.x;
    if (tx >= OUTLEN / 8) return;
    const int b  = blockIdx.y;
    const int n0 = tx * 8;
    const int p0 = n0 + 1024;
    int tmin = (p0 - 1536) >> 9;  if (tmin < 0) tmin = 0;
    int tmax = p0 >> 9;           if (tmax > TFRAMES - 1) tmax = TFRAMES - 1;

    float acc[8], ws[8];
    #pragma unroll
    for (int j = 0; j < 8; ++j) { acc[j] = 0.0f; ws[j] = 0.0f; }

    for (int t = tmin; t <= tmax; ++t) {
        const int a0 = p0 - t * HOPSZ;        // 8-run fully inside [0,2048)
        const uint4 pv = *(const uint4*)(Y + ((size_t)(b * 4 + (t & 3))) * TOTALP + p0);
        const unsigned pw[4] = {pv.x, pv.y, pv.z, pv.w};
        const float4 w0 = *(const float4*)(win2 + a0);
        const float4 w1 = *(const float4*)(win2 + a0 + 4);
        #pragma unroll
        for (int j = 0; j < 4; ++j) {
            acc[2 * j]     += bf2f((unsigned short)(pw[j] & 0xffffu));
            acc[2 * j + 1] += bf2f((unsigned short)(pw[j] >> 16));
        }
        ws[0] += w0.x; ws[1] += w0.y; ws[2] += w0.z; ws[3] += w0.w;
        ws[4] += w1.x; ws[5] += w1.y; ws[6] += w1.z; ws[7] += w1.w;
    }
    float r[8];
    #pragma unroll
    for (int j = 0; j < 8; ++j) r[j] = acc[j] / fmaxf(ws[j], 1e-8f);
    float4* o = (float4*)(out + (size_t)b * OUTLEN + n0);
    o[0] = float4{r[0], r[1], r[2], r[3]};
    o[1] = float4{r[4], r[5], r[6], r[7]};
}

// ---------------- launch -----------------------------------------------------
extern "C" void kernel_launch(void* const* d_in, const int* in_sizes, int n_in,
                              void* d_out, int out_size, void* d_ws, size_t ws_size,
                              hipStream_t stream) {
    const float* re = (const float*)d_in[0];
    const float* im = (const float*)d_in[1];
    float* out = (float*)d_out;

    char* ws = (char*)d_ws;
    unsigned short* Y    = (unsigned short*)(ws);            // 8*4*1050112*2 = 67,207,168 B
    float*          win2 = (float*)        (ws + 67207168);  // 8,192 B

    build_tabs<<<dim3(8),      256, 0, stream>>>(win2);
    fft_frames<<<dim3(MROWS),  256, 0, stream>>>(re, im, Y);
    final_pass<<<dim3(512, BATCH), 256, 0, stream>>>(Y, win2, out);
}

// Round 9
// 74.076 us; speedup vs baseline: 3.3713x; 1.3220x over previous
//
#include <hip/hip_runtime.h>

// ---------------- problem constants ----------------
#define NFFT    2048
#define HOPSZ   512
#define BATCH   8
#define TFRAMES 2048
#define FBINS   1025
#define OUTLEN  1048064           // HOP*(T-1)
#define TOTALP  1050112           // NFFT + HOP*(T-1)
#define MROWS   16384             // BATCH*TFRAMES

// tabs layout (float2 units):
//   [0..255]     T1[k]  = e^{+2pi i k/1024}
//   [256..511]   T2[k]  = e^{+2pi i 2k/1024}
//   [512..767]   T3[k]  = e^{+2pi i 3k/1024}
//   [768..1791]  TWP[m] = e^{+i pi m/1024}        (irfft pack twiddles)
//   [1792..2815] WPAIR[n] = (win[2n], win[2n+1])  (hann window pairs)

__device__ __forceinline__ unsigned short f2bf(float f) {
    unsigned u = __float_as_uint(f);
    u += 0x7fffu + ((u >> 16) & 1u);       // round-to-nearest-even
    return (unsigned short)(u >> 16);
}
__device__ __forceinline__ float bf2f(unsigned short h) {
    return __uint_as_float(((unsigned)h) << 16);
}

__global__ void build_tabs(float2* __restrict__ tabs) {
    int i = blockIdx.x * 256 + threadIdx.x;       // 0..2815
    if (i < 256) {
        tabs[i] = float2{cospif((float)i * (1.0f / 512.0f)),
                         sinpif((float)i * (1.0f / 512.0f))};
    } else if (i < 512) {
        int k = i - 256;
        tabs[i] = float2{cospif((float)k * (1.0f / 256.0f)),
                         sinpif((float)k * (1.0f / 256.0f))};
    } else if (i < 768) {
        int k = 3 * (i - 512);
        tabs[i] = float2{cospif((float)k * (1.0f / 512.0f)),
                         sinpif((float)k * (1.0f / 512.0f))};
    } else if (i < 1792) {
        int m = i - 768;
        tabs[i] = float2{cospif((float)m * (1.0f / 1024.0f)),
                         sinpif((float)m * (1.0f / 1024.0f))};
    } else if (i < 2816) {
        int n = i - 1792;
        tabs[i] = float2{0.5f - 0.5f * cospif((float)(2 * n)     * (1.0f / 1024.0f)),
                         0.5f - 0.5f * cospif((float)(2 * n + 1) * (1.0f / 1024.0f))};
    }
}

// ---------------- per-frame inverse real FFT (radix-4 Stockham) -------------
// One 256-thread block per frame. irfft pack (verified r7), then 5 radix-4
// Stockham stages (e^{+i} kernel; butterfly verified at N=4), then window +
// bf16 store into disjoint OLA plane Y[b][t&3][t*512+a]. All twiddles/windows
// from tables — zero runtime transcendentals.
__global__ __launch_bounds__(256) void fft_frames(
    const float* __restrict__ re, const float* __restrict__ im,
    const float2* __restrict__ tabs,
    unsigned short* __restrict__ Y)          // [BATCH][4][TOTALP] bf16
{
    __shared__ float2 buf[2048];             // ping-pong halves
    __shared__ float2 Tl[768];               // T1|T2|T3 stage twiddles

    const int u     = threadIdx.x;
    const int frame = blockIdx.x;
    const int b     = frame >> 11;
    const int t     = frame & (TFRAMES - 1);
    const float* rr = re + (size_t)frame * FBINS;
    const float* ii = im + (size_t)frame * FBINS;

    #pragma unroll
    for (int g = 0; g < 3; ++g)
        Tl[u + 256 * g] = tabs[u + 256 * g];

    // ---- pack Z into buf[0..1023] ----
    #pragma unroll
    for (int h = 0; h < 4; ++h) {
        int m = u + 256 * h;
        float Zr, Zi;
        if (m == 0) {
            float r0 = rr[0], rN = rr[1024];
            Zr = r0 + rN; Zi = r0 - rN;
        } else {
            float  Xr = rr[m],        Xi = ii[m];
            float  Cr = rr[1024 - m], Ni = ii[1024 - m];   // Ci = -Ni
            float2 W  = tabs[768 + m];
            float Er = Xr + Cr, Ei = Xi - Ni;
            float Or = Xr - Cr, Oi = Xi + Ni;
            Zr = Er - (W.x * Oi + W.y * Or);
            Zi = Ei + (W.x * Or - W.y * Oi);
        }
        buf[m] = float2{Zr, Zi};
    }
    __syncthreads();

    // ---- 5 radix-4 Stockham stages (inverse kernel) ----
    #pragma unroll
    for (int st = 0; st < 5; ++st) {
        const int s    = 1 << (2 * st);
        const int q    = u & (s - 1);
        const int k    = u - q;              // twiddle index, < 256
        const int srcO = (st & 1) ? 1024 : 0;
        const int dstO = 1024 - srcO;
        float2 a = buf[srcO + u];
        float2 bb = buf[srcO + u + 256];
        float2 c = buf[srcO + u + 512];
        float2 d = buf[srcO + u + 768];
        float apcx = a.x + c.x,  apcy = a.y + c.y;
        float amcx = a.x - c.x,  amcy = a.y - c.y;
        float bpdx = bb.x + d.x, bpdy = bb.y + d.y;
        float bmdx = bb.x - d.x, bmdy = bb.y - d.y;
        float2 y0 = float2{apcx + bpdx, apcy + bpdy};
        float2 u1 = float2{amcx - bmdy, amcy + bmdx};   // amc + j*bmd
        float2 u2 = float2{apcx - bpdx, apcy - bpdy};
        float2 u3 = float2{amcx + bmdy, amcy - bmdx};   // amc - j*bmd
        float2 y1, y2, y3;
        if (st < 4) {
            float2 w1 = Tl[k], w2 = Tl[256 + k], w3 = Tl[512 + k];
            y1 = float2{w1.x * u1.x - w1.y * u1.y, w1.x * u1.y + w1.y * u1.x};
            y2 = float2{w2.x * u2.x - w2.y * u2.y, w2.x * u2.y + w2.y * u2.x};
            y3 = float2{w3.x * u3.x - w3.y * u3.y, w3.x * u3.y + w3.y * u3.x};
        } else {                              // s=256: all twiddles = 1
            y1 = u1; y2 = u2; y3 = u3;
        }
        const int base = dstO + 4 * u - 3 * q;
        buf[base]         = y0;
        buf[base + s]     = y1;
        buf[base + 2 * s] = y2;
        buf[base + 3 * s] = y3;
        __syncthreads();
    }
    // result z[n] in buf[1024..2047]

    // ---- unpack + window + bf16 plane store ----
    unsigned short* Yb = Y + ((size_t)(b * 4 + (t & 3))) * TOTALP + t * HOPSZ;
    const float sc = 1.0f / 2048.0f;
    #pragma unroll
    for (int h = 0; h < 4; ++h) {
        int n = u + 256 * h;
        float2 z = buf[1024 + n];
        float2 wp = tabs[1792 + n];
        unsigned pack = ((unsigned)f2bf(z.y * sc * wp.y) << 16)
                      |  (unsigned)f2bf(z.x * sc * wp.x);
        *(unsigned*)(Yb + 2 * n) = pack;
    }
}

// ---------------- final pass: gather 4 planes, divide by window-sumsquare ---
__global__ __launch_bounds__(256) void final_pass(
    const unsigned short* __restrict__ Y,    // [BATCH][4][TOTALP]
    const float2*         __restrict__ tabs, // WPAIR at 1792 (win^2 via w*w)
    float*                __restrict__ out)  // [BATCH][OUTLEN]
{
    const int tx = blockIdx.x * 256 + threadIdx.x;
    if (tx >= OUTLEN / 8) return;
    const int b  = blockIdx.y;
    const int n0 = tx * 8;
    const int p0 = n0 + 1024;
    int tmin = (p0 - 1536) >> 9;  if (tmin < 0) tmin = 0;
    int tmax = p0 >> 9;           if (tmax > TFRAMES - 1) tmax = TFRAMES - 1;

    float acc[8], ws[8];
    #pragma unroll
    for (int j = 0; j < 8; ++j) { acc[j] = 0.0f; ws[j] = 0.0f; }

    for (int t = tmin; t <= tmax; ++t) {
        const int a0 = p0 - t * HOPSZ;        // 8-run fully inside [0,2048)
        const uint4 pv = *(const uint4*)(Y + ((size_t)(b * 4 + (t & 3))) * TOTALP + p0);
        const unsigned pw[4] = {pv.x, pv.y, pv.z, pv.w};
        #pragma unroll
        for (int j = 0; j < 4; ++j) {
            acc[2 * j]     += bf2f((unsigned short)(pw[j] & 0xffffu));
            acc[2 * j + 1] += bf2f((unsigned short)(pw[j] >> 16));
        }
        #pragma unroll
        for (int j = 0; j < 4; ++j) {
            float2 w = tabs[1792 + (a0 >> 1) + j];    // (win[a0+2j], win[a0+2j+1])
            ws[2 * j]     += w.x * w.x;
            ws[2 * j + 1] += w.y * w.y;
        }
    }
    float r[8];
    #pragma unroll
    for (int j = 0; j < 8; ++j) r[j] = acc[j] / fmaxf(ws[j], 1e-8f);
    float4* o = (float4*)(out + (size_t)b * OUTLEN + n0);
    o[0] = float4{r[0], r[1], r[2], r[3]};
    o[1] = float4{r[4], r[5], r[6], r[7]};
}

// ---------------- launch -----------------------------------------------------
extern "C" void kernel_launch(void* const* d_in, const int* in_sizes, int n_in,
                              void* d_out, int out_size, void* d_ws, size_t ws_size,
                              hipStream_t stream) {
    const float* re = (const float*)d_in[0];
    const float* im = (const float*)d_in[1];
    float* out = (float*)d_out;

    char* ws = (char*)d_ws;
    unsigned short* Y    = (unsigned short*)(ws);            // 8*4*1050112*2 = 67,207,168 B
    float2*         tabs = (float2*)       (ws + 67207168);  // 2816*8 = 22,528 B

    build_tabs<<<dim3(11),     256, 0, stream>>>(tabs);
    fft_frames<<<dim3(MROWS),  256, 0, stream>>>(re, im, tabs, Y);
    final_pass<<<dim3(512, BATCH), 256, 0, stream>>>(Y, tabs, out);
}